// Round 6
// baseline (14.804 us; speedup 1.0000x reference)
//
#include <hip/hip_runtime.h>
#include <math.h>

// DenseMLPQMatrixDecoder, fused single kernel.
// Q depends only on v; expm(1000*Q) == stationary pi whenever all nonzero
// eigenvalues have Re mu < -delta (Routh-Hurwitz gate on the shifted
// characteristic cubic -- pure arithmetic). Fast path: pi via Markov-tree
// theorem (diagonal 3x3 cofactors, fp64). The four cofactors double as the
// char-poly coefficient e3, so the gate is nearly free. Fallback (marginal
// gap): fp64 scaling-and-squaring expm. Then broadcast across S=1024 sites.

namespace {

constexpr int kA = 4;
constexpr int kD = 8;
constexpr int kW = 16;
constexpr int kV = 1024;
constexpr int kS = 1024;
constexpr int kSquarings = 14;   // fallback: 2^14; tau = 1000/16384
constexpr int kTaylorOrder = 8;

typedef float f32x2 __attribute__((ext_vector_type(2)));

__device__ inline double det3(double m00, double m01, double m02,
                              double m10, double m11, double m12,
                              double m20, double m21, double m22) {
  return m00 * (m11 * m22 - m12 * m21) -
         m01 * (m10 * m22 - m12 * m20) +
         m02 * (m10 * m21 - m11 * m20);
}

__global__ __launch_bounds__(64) void fused_kernel(
    const float* __restrict__ emb,
    const float* __restrict__ W0,
    const float* __restrict__ b0,
    const float* __restrict__ W1,
    const float* __restrict__ b1,
    const float* __restrict__ Wout,
    const float* __restrict__ bout,
    float4* __restrict__ out) {
  const int v = blockIdx.x;

  // ---- MLP: D -> W -> W -> A*A, packed-fp32 (v_pk_fma_f32) ----
  float x[kD];
#pragma unroll
  for (int d = 0; d < kD; ++d) x[d] = emb[v * kD + d];

  f32x2 a0v[kW / 2];
#pragma unroll
  for (int j = 0; j < kW / 2; ++j) a0v[j] = ((const f32x2*)b0)[j];
#pragma unroll
  for (int d = 0; d < kD; ++d) {
    const f32x2 xv = {x[d], x[d]};
    const f32x2* wr = (const f32x2*)(W0 + d * kW);
#pragma unroll
    for (int j = 0; j < kW / 2; ++j)
      a0v[j] = __builtin_elementwise_fma(xv, wr[j], a0v[j]);
  }
  float h0[kW];
#pragma unroll
  for (int j = 0; j < kW / 2; ++j) {
    h0[2 * j]     = fmaxf(a0v[j][0], 0.0f);
    h0[2 * j + 1] = fmaxf(a0v[j][1], 0.0f);
  }

  f32x2 a1v[kW / 2];
#pragma unroll
  for (int j = 0; j < kW / 2; ++j) a1v[j] = ((const f32x2*)b1)[j];
#pragma unroll
  for (int k = 0; k < kW; ++k) {
    const f32x2 hv = {h0[k], h0[k]};
    const f32x2* wr = (const f32x2*)(W1 + k * kW);
#pragma unroll
    for (int j = 0; j < kW / 2; ++j)
      a1v[j] = __builtin_elementwise_fma(hv, wr[j], a1v[j]);
  }
  float h1[kW];
#pragma unroll
  for (int j = 0; j < kW / 2; ++j) {
    h1[2 * j]     = fmaxf(a1v[j][0], 0.0f);
    h1[2 * j + 1] = fmaxf(a1v[j][1], 0.0f);
  }

  f32x2 lv[kA * kA / 2];
#pragma unroll
  for (int j = 0; j < kA * kA / 2; ++j) lv[j] = ((const f32x2*)bout)[j];
#pragma unroll
  for (int k = 0; k < kW; ++k) {
    const f32x2 hv = {h1[k], h1[k]};
    const f32x2* wr = (const f32x2*)(Wout + k * (kA * kA));
#pragma unroll
    for (int j = 0; j < kA * kA / 2; ++j)
      lv[j] = __builtin_elementwise_fma(hv, wr[j], lv[j]);
  }
  float l[kA * kA];
#pragma unroll
  for (int j = 0; j < kA * kA / 2; ++j) {
    l[2 * j]     = lv[j][0];
    l[2 * j + 1] = lv[j][1];
  }

  // ---- Q = P - I; P = per-row off-diagonal softmax ----
  double Q[kA][kA];
#pragma unroll
  for (int i = 0; i < kA; ++i) {
    float m = -3.0e38f;
#pragma unroll
    for (int j = 0; j < kA; ++j)
      if (j != i) m = fmaxf(m, l[i * kA + j]);
    float e[kA];
    float ssumf = 0.0f;
#pragma unroll
    for (int j = 0; j < kA; ++j) {
      e[j] = (j == i) ? 0.0f : __expf(l[i * kA + j] - m);
      ssumf += e[j];
    }
    const float inv = 1.0f / ssumf;
#pragma unroll
    for (int j = 0; j < kA; ++j)
      Q[i][j] = (j == i) ? -1.0 : (double)(e[j] * inv);
  }

  // ---- cofactors (tree theorem) -- also e3 of the char poly ----
  const double c0 = det3(Q[1][1], Q[1][2], Q[1][3],
                         Q[2][1], Q[2][2], Q[2][3],
                         Q[3][1], Q[3][2], Q[3][3]);
  const double c1 = det3(Q[0][0], Q[0][2], Q[0][3],
                         Q[2][0], Q[2][2], Q[2][3],
                         Q[3][0], Q[3][2], Q[3][3]);
  const double c2 = det3(Q[0][0], Q[0][1], Q[0][3],
                         Q[1][0], Q[1][1], Q[1][3],
                         Q[3][0], Q[3][1], Q[3][3]);
  const double c3 = det3(Q[0][0], Q[0][1], Q[0][2],
                         Q[1][0], Q[1][1], Q[1][2],
                         Q[2][0], Q[2][1], Q[2][2]);
  const double csum = c0 + c1 + c2 + c3;  // = e3

  // e2 = sum of 2x2 principal minors; Q_ii = -1 exactly -> 6 - sum Qij*Qji.
  double s2 = 0.0;
#pragma unroll
  for (int i = 0; i < kA; ++i)
#pragma unroll
    for (int j = i + 1; j < kA; ++j) s2 = fma(Q[i][j], Q[j][i], s2);
  const double e2 = 6.0 - s2;

  // Routh-Hurwitz on f(mu) = mu^3 + 4 mu^2 + e2 mu + a0, a0 = -e3,
  // shifted by delta: all roots have Re mu < -delta iff a1s, a0s > 0 and
  // a2s*a1s > a0s (a2s = 4 - 3*delta > 0 always).
  constexpr double dlt = 0.03;
  const double a0 = -csum;
  const double a2s = 4.0 - 3.0 * dlt;
  const double a1s = e2 - 8.0 * dlt + 3.0 * dlt * dlt;
  const double a0s = a0 - e2 * dlt + 4.0 * dlt * dlt - dlt * dlt * dlt;
  const bool fast = (a1s > 0.0) && (a0s > 0.0) && (a2s * a1s > a0s);

  float4 rvec;
  if (fast) {
    const double inv = 1.0 / csum;
    rvec = make_float4((float)(c0 * inv), (float)(c1 * inv),
                       (float)(c2 * inv), (float)(c3 * inv));
  } else {
    // ---- fallback: fp64 scaling-and-squaring expm(1000*Q) ----
    const double tau = 1000.0 / (double)(1 << kSquarings);
    double M[kA][kA];
#pragma unroll
    for (int i = 0; i < kA; ++i)
#pragma unroll
      for (int j = 0; j < kA; ++j) M[i][j] = tau * Q[i][j];

    double T[kA][kA];
#pragma unroll
    for (int i = 0; i < kA; ++i)
#pragma unroll
      for (int j = 0; j < kA; ++j) T[i][j] = (i == j) ? 1.0 : 0.0;

#pragma unroll 1
    for (int k = kTaylorOrder; k >= 1; --k) {
      double U[kA][kA];
#pragma unroll
      for (int i = 0; i < kA; ++i)
#pragma unroll
        for (int j = 0; j < kA; ++j) {
          double acc = 0.0;
#pragma unroll
          for (int p = 0; p < kA; ++p) acc = fma(M[i][p], T[p][j], acc);
          U[i][j] = acc;
        }
      const double rk = 1.0 / (double)k;
#pragma unroll
      for (int i = 0; i < kA; ++i)
#pragma unroll
        for (int j = 0; j < kA; ++j)
          T[i][j] = ((i == j) ? 1.0 : 0.0) + U[i][j] * rk;
    }

#pragma unroll 1
    for (int t = 0; t < kSquarings - 1; ++t) {
      double U[kA][kA];
#pragma unroll
      for (int i = 0; i < kA; ++i)
#pragma unroll
        for (int j = 0; j < kA; ++j) {
          double acc = 0.0;
#pragma unroll
          for (int p = 0; p < kA; ++p) acc = fma(T[i][p], T[p][j], acc);
          U[i][j] = acc;
        }
#pragma unroll
      for (int i = 0; i < kA; ++i)
#pragma unroll
        for (int j = 0; j < kA; ++j) T[i][j] = U[i][j];
    }

    double r0[kA];
#pragma unroll
    for (int j = 0; j < kA; ++j) {
      double acc = 0.0;
#pragma unroll
      for (int p = 0; p < kA; ++p) acc = fma(T[0][p], T[p][j], acc);
      r0[j] = acc;
    }
    rvec = make_float4((float)r0[0], (float)r0[1], (float)r0[2], (float)r0[3]);
  }

  // ---- broadcast across S sites: 16 coalesced float4 stores per lane ----
  float4* o = out + (size_t)v * kS;
#pragma unroll
  for (int k = 0; k < kS / 64; ++k) o[k * 64 + threadIdx.x] = rvec;
}

}  // namespace

extern "C" void kernel_launch(void* const* d_in, const int* in_sizes, int n_in,
                              void* d_out, int out_size, void* d_ws,
                              size_t ws_size, hipStream_t stream) {
  const float* emb  = (const float*)d_in[0];
  // d_in[1] = site_positions_SxC: unused (output is independent of positions)
  const float* W0   = (const float*)d_in[2];
  const float* b0   = (const float*)d_in[3];
  const float* W1   = (const float*)d_in[4];
  const float* b1   = (const float*)d_in[5];
  const float* Wout = (const float*)d_in[6];
  const float* bout = (const float*)d_in[7];

  fused_kernel<<<kV, 64, 0, stream>>>(emb, W0, b0, W1, b1, Wout, bout,
                                      (float4*)d_out);
}

// Round 7
// 12.383 us; speedup vs baseline: 1.1955x; 1.1955x over previous
//
#include <hip/hip_runtime.h>
#include <math.h>

// DenseMLPQMatrixDecoder, fused single kernel.
// Q depends only on v; expm(1000*Q) == stationary pi whenever all nonzero
// eigenvalues have Re mu < -delta (Routh-Hurwitz gate on the shifted
// characteristic cubic -- pure arithmetic, no transcendentals). Fast path:
// pi via Markov-tree theorem (diagonal 3x3 cofactors, fp64); the cofactor
// sum doubles as char-poly coefficient e3, so the gate is nearly free.
// Fallback (marginal spectral gap): fp64 scaling-and-squaring expm.
// Then all 64 lanes broadcast the float4 across S=1024 sites.
// NOTE: MLP stays SCALAR fp32 -- wave-uniform weight addresses hoist into
// SGPRs (s_load); R6's f32x2 packing broke that and cost ~2us.

namespace {

constexpr int kA = 4;
constexpr int kD = 8;
constexpr int kW = 16;
constexpr int kV = 1024;
constexpr int kS = 1024;
constexpr int kSquarings = 14;   // fallback: 2^14; tau = 1000/16384
constexpr int kTaylorOrder = 8;

__device__ inline double det3(double m00, double m01, double m02,
                              double m10, double m11, double m12,
                              double m20, double m21, double m22) {
  return m00 * (m11 * m22 - m12 * m21) -
         m01 * (m10 * m22 - m12 * m20) +
         m02 * (m10 * m21 - m11 * m20);
}

__global__ __launch_bounds__(64) void fused_kernel(
    const float* __restrict__ emb,
    const float* __restrict__ W0,
    const float* __restrict__ b0,
    const float* __restrict__ W1,
    const float* __restrict__ b1,
    const float* __restrict__ Wout,
    const float* __restrict__ bout,
    float4* __restrict__ out) {
  const int v = blockIdx.x;

  // ---- MLP: D -> W -> W -> A*A (ReLU hidden); scalar, SGPR weights ----
  float x[kD];
#pragma unroll
  for (int d = 0; d < kD; ++d) x[d] = emb[v * kD + d];

  float h0[kW];
#pragma unroll
  for (int j = 0; j < kW; ++j) {
    float acc = b0[j];
#pragma unroll
    for (int d = 0; d < kD; ++d) acc = fmaf(x[d], W0[d * kW + j], acc);
    h0[j] = fmaxf(acc, 0.0f);
  }

  float h1[kW];
#pragma unroll
  for (int j = 0; j < kW; ++j) {
    float acc = b1[j];
#pragma unroll
    for (int k = 0; k < kW; ++k) acc = fmaf(h0[k], W1[k * kW + j], acc);
    h1[j] = fmaxf(acc, 0.0f);
  }

  float l[kA * kA];
#pragma unroll
  for (int j = 0; j < kA * kA; ++j) {
    float acc = bout[j];
#pragma unroll
    for (int k = 0; k < kW; ++k)
      acc = fmaf(h1[k], Wout[k * (kA * kA) + j], acc);
    l[j] = acc;
  }

  // ---- Q = P - I; P = per-row off-diagonal softmax ----
  double Q[kA][kA];
#pragma unroll
  for (int i = 0; i < kA; ++i) {
    float m = -3.0e38f;
#pragma unroll
    for (int j = 0; j < kA; ++j)
      if (j != i) m = fmaxf(m, l[i * kA + j]);
    float e[kA];
    float ssumf = 0.0f;
#pragma unroll
    for (int j = 0; j < kA; ++j) {
      e[j] = (j == i) ? 0.0f : __expf(l[i * kA + j] - m);
      ssumf += e[j];
    }
    const float inv = 1.0f / ssumf;
#pragma unroll
    for (int j = 0; j < kA; ++j)
      Q[i][j] = (j == i) ? -1.0 : (double)(e[j] * inv);
  }

  // ---- cofactors (tree theorem) -- their sum is char-poly e3 ----
  const double c0 = det3(Q[1][1], Q[1][2], Q[1][3],
                         Q[2][1], Q[2][2], Q[2][3],
                         Q[3][1], Q[3][2], Q[3][3]);
  const double c1 = det3(Q[0][0], Q[0][2], Q[0][3],
                         Q[2][0], Q[2][2], Q[2][3],
                         Q[3][0], Q[3][2], Q[3][3]);
  const double c2 = det3(Q[0][0], Q[0][1], Q[0][3],
                         Q[1][0], Q[1][1], Q[1][3],
                         Q[3][0], Q[3][1], Q[3][3]);
  const double c3 = det3(Q[0][0], Q[0][1], Q[0][2],
                         Q[1][0], Q[1][1], Q[1][2],
                         Q[2][0], Q[2][1], Q[2][2]);
  const double csum = c0 + c1 + c2 + c3;  // = e3

  // e2 = sum of 2x2 principal minors; Q_ii = -1 exactly -> 6 - sum Qij*Qji.
  double s2 = 0.0;
#pragma unroll
  for (int i = 0; i < kA; ++i)
#pragma unroll
    for (int j = i + 1; j < kA; ++j) s2 = fma(Q[i][j], Q[j][i], s2);
  const double e2 = 6.0 - s2;

  // Routh-Hurwitz on f(mu) = mu^3 + 4 mu^2 + e2 mu + a0, a0 = -e3, shifted
  // by delta: all roots have Re mu < -delta iff a1s, a0s > 0, a2s*a1s > a0s.
  constexpr double dlt = 0.03;
  const double a0 = -csum;
  const double a2s = 4.0 - 3.0 * dlt;
  const double a1s = e2 - 8.0 * dlt + 3.0 * dlt * dlt;
  const double a0s = a0 - e2 * dlt + 4.0 * dlt * dlt - dlt * dlt * dlt;
  const bool fast = (a1s > 0.0) && (a0s > 0.0) && (a2s * a1s > a0s);

  float4 rvec;
  if (fast) {
    const double inv = 1.0 / csum;
    rvec = make_float4((float)(c0 * inv), (float)(c1 * inv),
                       (float)(c2 * inv), (float)(c3 * inv));
  } else {
    // ---- fallback: fp64 scaling-and-squaring expm(1000*Q) ----
    const double tau = 1000.0 / (double)(1 << kSquarings);
    double M[kA][kA];
#pragma unroll
    for (int i = 0; i < kA; ++i)
#pragma unroll
      for (int j = 0; j < kA; ++j) M[i][j] = tau * Q[i][j];

    double T[kA][kA];
#pragma unroll
    for (int i = 0; i < kA; ++i)
#pragma unroll
      for (int j = 0; j < kA; ++j) T[i][j] = (i == j) ? 1.0 : 0.0;

#pragma unroll 1
    for (int k = kTaylorOrder; k >= 1; --k) {
      double U[kA][kA];
#pragma unroll
      for (int i = 0; i < kA; ++i)
#pragma unroll
        for (int j = 0; j < kA; ++j) {
          double acc = 0.0;
#pragma unroll
          for (int p = 0; p < kA; ++p) acc = fma(M[i][p], T[p][j], acc);
          U[i][j] = acc;
        }
      const double rk = 1.0 / (double)k;
#pragma unroll
      for (int i = 0; i < kA; ++i)
#pragma unroll
        for (int j = 0; j < kA; ++j)
          T[i][j] = ((i == j) ? 1.0 : 0.0) + U[i][j] * rk;
    }

#pragma unroll 1
    for (int t = 0; t < kSquarings - 1; ++t) {
      double U[kA][kA];
#pragma unroll
      for (int i = 0; i < kA; ++i)
#pragma unroll
        for (int j = 0; j < kA; ++j) {
          double acc = 0.0;
#pragma unroll
          for (int p = 0; p < kA; ++p) acc = fma(T[i][p], T[p][j], acc);
          U[i][j] = acc;
        }
#pragma unroll
      for (int i = 0; i < kA; ++i)
#pragma unroll
        for (int j = 0; j < kA; ++j) T[i][j] = U[i][j];
    }

    double r0[kA];
#pragma unroll
    for (int j = 0; j < kA; ++j) {
      double acc = 0.0;
#pragma unroll
      for (int p = 0; p < kA; ++p) acc = fma(T[0][p], T[p][j], acc);
      r0[j] = acc;
    }
    rvec = make_float4((float)r0[0], (float)r0[1], (float)r0[2], (float)r0[3]);
  }

  // ---- broadcast across S sites: 16 coalesced float4 stores per lane ----
  float4* o = out + (size_t)v * kS;
#pragma unroll
  for (int k = 0; k < kS / 64; ++k) o[k * 64 + threadIdx.x] = rvec;
}

}  // namespace

extern "C" void kernel_launch(void* const* d_in, const int* in_sizes, int n_in,
                              void* d_out, int out_size, void* d_ws,
                              size_t ws_size, hipStream_t stream) {
  const float* emb  = (const float*)d_in[0];
  // d_in[1] = site_positions_SxC: unused (output is independent of positions)
  const float* W0   = (const float*)d_in[2];
  const float* b0   = (const float*)d_in[3];
  const float* W1   = (const float*)d_in[4];
  const float* b1   = (const float*)d_in[5];
  const float* Wout = (const float*)d_in[6];
  const float* bout = (const float*)d_in[7];

  fused_kernel<<<kV, 64, 0, stream>>>(emb, W0, b0, W1, b1, Wout, bout,
                                      (float4*)d_out);
}

// Round 8
// 11.404 us; speedup vs baseline: 1.2981x; 1.0858x over previous
//
#include <hip/hip_runtime.h>
#include <math.h>

// DenseMLPQMatrixDecoder, fused single kernel, lane-parallel MLP.
// Q depends only on v; expm(1000*Q) == stationary pi whenever all nonzero
// eigenvalues have Re mu < -delta (Routh-Hurwitz gate on the shifted
// characteristic cubic -- pure arithmetic). Fast path: pi via Markov-tree
// theorem (diagonal 3x3 cofactors, fp64); the cofactor sum doubles as
// char-poly e3. Fallback (marginal gap): fp64 scaling-and-squaring expm.
//
// MLP is lane-parallel: neuron n = lane&15 per lane (weight COLUMN loads are
// per-lane, coalesced; hidden vector broadcast between layers via __shfl).
// Softmax is lane-parallel in 4-lane row groups (plain exp, like the
// reference -- no max subtraction). Q is then gathered into every lane (fp64)
// for the gate/cofactors. All 64 lanes broadcast the float4 over S sites.

namespace {

constexpr int kA = 4;
constexpr int kD = 8;
constexpr int kW = 16;
constexpr int kV = 1024;
constexpr int kS = 1024;
constexpr int kSquarings = 14;   // fallback: 2^14; tau = 1000/16384
constexpr int kTaylorOrder = 8;

__device__ inline double det3(double m00, double m01, double m02,
                              double m10, double m11, double m12,
                              double m20, double m21, double m22) {
  return m00 * (m11 * m22 - m12 * m21) -
         m01 * (m10 * m22 - m12 * m20) +
         m02 * (m10 * m21 - m11 * m20);
}

__global__ __launch_bounds__(64) void fused_kernel(
    const float* __restrict__ emb,
    const float* __restrict__ W0,
    const float* __restrict__ b0,
    const float* __restrict__ W1,
    const float* __restrict__ b1,
    const float* __restrict__ Wout,
    const float* __restrict__ bout,
    float4* __restrict__ out) {
  const int v = blockIdx.x;
  const int lane = threadIdx.x;
  const int n = lane & 15;  // neuron / matrix-entry index (4x replicated)

  // ---- per-lane weight columns (coalesced, L2-hot after first blocks) ----
  float w0c[kD];
#pragma unroll
  for (int d = 0; d < kD; ++d) w0c[d] = W0[d * kW + n];
  float w1c[kW];
#pragma unroll
  for (int k = 0; k < kW; ++k) w1c[k] = W1[k * kW + n];
  float woc[kW];
#pragma unroll
  for (int k = 0; k < kW; ++k) woc[k] = Wout[k * (kA * kA) + n];
  const float b0n = b0[n];
  const float b1n = b1[n];
  const float botn = bout[n];

  // ---- uniform input row (wave-uniform address -> scalar loads) ----
  float x[kD];
#pragma unroll
  for (int d = 0; d < kD; ++d) x[d] = emb[v * kD + d];

  // ---- layer 0: h0[n] in lane n ----
  float acc = b0n;
#pragma unroll
  for (int d = 0; d < kD; ++d) acc = fmaf(x[d], w0c[d], acc);
  const float h0 = fmaxf(acc, 0.0f);

  // ---- layer 1: broadcast h0 across lanes ----
  acc = b1n;
#pragma unroll
  for (int k = 0; k < kW; ++k) acc = fmaf(__shfl(h0, k), w1c[k], acc);
  const float h1 = fmaxf(acc, 0.0f);

  // ---- output layer: logit for entry n = 4*i + j ----
  acc = botn;
#pragma unroll
  for (int k = 0; k < kW; ++k) acc = fmaf(__shfl(h1, k), woc[k], acc);
  const float ln = acc;

  // ---- row softmax in 4-lane groups (plain exp, as the reference) ----
  const int ri = n >> 2, cj = n & 3;
  const float e = (ri == cj) ? 0.0f : __expf(ln);
  float s = e + __shfl_xor(e, 1);
  s = s + __shfl_xor(s, 2);
  const float qf = e * (1.0f / s);  // off-diagonal P entry for this lane

  // ---- gather Q into every lane (fp64); diagonal exactly -1 ----
  double Q[kA][kA];
#pragma unroll
  for (int m = 0; m < kA * kA; ++m) Q[m >> 2][m & 3] = (double)__shfl(qf, m);
#pragma unroll
  for (int i = 0; i < kA; ++i) Q[i][i] = -1.0;

  // ---- cofactors (tree theorem) -- their sum is char-poly e3 ----
  const double c0 = det3(Q[1][1], Q[1][2], Q[1][3],
                         Q[2][1], Q[2][2], Q[2][3],
                         Q[3][1], Q[3][2], Q[3][3]);
  const double c1 = det3(Q[0][0], Q[0][2], Q[0][3],
                         Q[2][0], Q[2][2], Q[2][3],
                         Q[3][0], Q[3][2], Q[3][3]);
  const double c2 = det3(Q[0][0], Q[0][1], Q[0][3],
                         Q[1][0], Q[1][1], Q[1][3],
                         Q[3][0], Q[3][1], Q[3][3]);
  const double c3 = det3(Q[0][0], Q[0][1], Q[0][2],
                         Q[1][0], Q[1][1], Q[1][2],
                         Q[2][0], Q[2][1], Q[2][2]);
  const double csum = c0 + c1 + c2 + c3;  // = e3

  // e2 = sum of 2x2 principal minors; Q_ii = -1 exactly -> 6 - sum Qij*Qji.
  double s2 = 0.0;
#pragma unroll
  for (int i = 0; i < kA; ++i)
#pragma unroll
    for (int j = i + 1; j < kA; ++j) s2 = fma(Q[i][j], Q[j][i], s2);
  const double e2 = 6.0 - s2;

  // Routh-Hurwitz on f(mu) = mu^3 + 4 mu^2 + e2 mu + a0, a0 = -e3, shifted
  // by delta: all roots have Re mu < -delta iff a1s, a0s > 0, a2s*a1s > a0s.
  constexpr double dlt = 0.03;
  const double a0 = -csum;
  const double a2s = 4.0 - 3.0 * dlt;
  const double a1s = e2 - 8.0 * dlt + 3.0 * dlt * dlt;
  const double a0s = a0 - e2 * dlt + 4.0 * dlt * dlt - dlt * dlt * dlt;
  const bool fast = (a1s > 0.0) && (a0s > 0.0) && (a2s * a1s > a0s);

  float4 rvec;
  if (fast) {
    const double inv = 1.0 / csum;
    rvec = make_float4((float)(c0 * inv), (float)(c1 * inv),
                       (float)(c2 * inv), (float)(c3 * inv));
  } else {
    // ---- fallback: fp64 scaling-and-squaring expm(1000*Q) ----
    const double tau = 1000.0 / (double)(1 << kSquarings);
    double M[kA][kA];
#pragma unroll
    for (int i = 0; i < kA; ++i)
#pragma unroll
      for (int j = 0; j < kA; ++j) M[i][j] = tau * Q[i][j];

    double T[kA][kA];
#pragma unroll
    for (int i = 0; i < kA; ++i)
#pragma unroll
      for (int j = 0; j < kA; ++j) T[i][j] = (i == j) ? 1.0 : 0.0;

#pragma unroll 1
    for (int k = kTaylorOrder; k >= 1; --k) {
      double U[kA][kA];
#pragma unroll
      for (int i = 0; i < kA; ++i)
#pragma unroll
        for (int j = 0; j < kA; ++j) {
          double a = 0.0;
#pragma unroll
          for (int p = 0; p < kA; ++p) a = fma(M[i][p], T[p][j], a);
          U[i][j] = a;
        }
      const double rk = 1.0 / (double)k;
#pragma unroll
      for (int i = 0; i < kA; ++i)
#pragma unroll
        for (int j = 0; j < kA; ++j)
          T[i][j] = ((i == j) ? 1.0 : 0.0) + U[i][j] * rk;
    }

#pragma unroll 1
    for (int t = 0; t < kSquarings - 1; ++t) {
      double U[kA][kA];
#pragma unroll
      for (int i = 0; i < kA; ++i)
#pragma unroll
        for (int j = 0; j < kA; ++j) {
          double a = 0.0;
#pragma unroll
          for (int p = 0; p < kA; ++p) a = fma(T[i][p], T[p][j], a);
          U[i][j] = a;
        }
#pragma unroll
      for (int i = 0; i < kA; ++i)
#pragma unroll
        for (int j = 0; j < kA; ++j) T[i][j] = U[i][j];
    }

    double r0[kA];
#pragma unroll
    for (int j = 0; j < kA; ++j) {
      double a = 0.0;
#pragma unroll
      for (int p = 0; p < kA; ++p) a = fma(T[0][p], T[p][j], a);
      r0[j] = a;
    }
    rvec = make_float4((float)r0[0], (float)r0[1], (float)r0[2], (float)r0[3]);
  }

  // ---- broadcast across S sites: 16 coalesced float4 stores per lane ----
  float4* o = out + (size_t)v * kS;
#pragma unroll
  for (int k = 0; k < kS / 64; ++k) o[k * 64 + threadIdx.x] = rvec;
}

}  // namespace

extern "C" void kernel_launch(void* const* d_in, const int* in_sizes, int n_in,
                              void* d_out, int out_size, void* d_ws,
                              size_t ws_size, hipStream_t stream) {
  const float* emb  = (const float*)d_in[0];
  // d_in[1] = site_positions_SxC: unused (output is independent of positions)
  const float* W0   = (const float*)d_in[2];
  const float* b0   = (const float*)d_in[3];
  const float* W1   = (const float*)d_in[4];
  const float* b1   = (const float*)d_in[5];
  const float* Wout = (const float*)d_in[6];
  const float* bout = (const float*)d_in[7];

  fused_kernel<<<kV, 64, 0, stream>>>(emb, W0, b0, W1, b1, Wout, bout,
                                      (float4*)d_out);
}